// Round 2
// baseline (10723.570 us; speedup 1.0000x reference)
//
#include <hip/hip_runtime.h>
#include <hip/hip_bf16.h>

// ---------------------------------------------------------------------------
// GEMM: C[M,N] = A[M,K] @ W[K,N] + bias[N]   (fp32 in/accum/out)
// 64x64 tile, BK=32, 256 threads, 4x4 micro-tile per thread.
// LDS layout: As[k][m] (k-major, transposed at stage-in), Bs[k][n];
// stride 68 floats keeps float4 alignment (272 B rows).
// ---------------------------------------------------------------------------
#define BM 64
#define BN 64
#define BK 32
#define LDT 68

__global__ __launch_bounds__(256) void gemm_bias_kernel(
    const float* __restrict__ A, const float* __restrict__ W,
    const float* __restrict__ bias, float* __restrict__ C,
    int M, int N, int K)
{
    __shared__ float As[BK * LDT];
    __shared__ float Bs[BK * LDT];

    const int tid = threadIdx.x;
    const int tx = tid & 15, ty = tid >> 4;
    const int row0 = blockIdx.y * BM;
    const int col0 = blockIdx.x * BN;

    float acc[4][4] = {};

    // A tile (64 rows x 32 k): 32B/thread; ar in [0,64), ac8 in {0,8,16,24}
    const int ar = tid >> 2, ac8 = (tid & 3) * 8;
    // B tile (32 k x 64 cols): 32B/thread; br in [0,32), bc8 in {0..56}
    const int br = tid >> 3, bc8 = (tid & 7) * 8;

    const float* Aptr = A + (size_t)(row0 + ar) * K + ac8;
    const float* Wptr = W + (size_t)br * N + col0 + bc8;

    for (int k0 = 0; k0 < K; k0 += BK) {
        float4 a0 = *(const float4*)(Aptr + k0);
        float4 a1 = *(const float4*)(Aptr + k0 + 4);
        float4 b0 = *(const float4*)(Wptr + (size_t)k0 * N);
        float4 b1 = *(const float4*)(Wptr + (size_t)k0 * N + 4);

        __syncthreads();  // previous tile fully consumed
        As[(ac8 + 0) * LDT + ar] = a0.x;
        As[(ac8 + 1) * LDT + ar] = a0.y;
        As[(ac8 + 2) * LDT + ar] = a0.z;
        As[(ac8 + 3) * LDT + ar] = a0.w;
        As[(ac8 + 4) * LDT + ar] = a1.x;
        As[(ac8 + 5) * LDT + ar] = a1.y;
        As[(ac8 + 6) * LDT + ar] = a1.z;
        As[(ac8 + 7) * LDT + ar] = a1.w;
        *(float4*)&Bs[br * LDT + bc8]     = b0;
        *(float4*)&Bs[br * LDT + bc8 + 4] = b1;
        __syncthreads();

#pragma unroll
        for (int kk = 0; kk < BK; kk++) {
            float4 a = *(const float4*)&As[kk * LDT + 4 * ty];
            float4 b = *(const float4*)&Bs[kk * LDT + 4 * tx];
            acc[0][0] += a.x * b.x; acc[0][1] += a.x * b.y; acc[0][2] += a.x * b.z; acc[0][3] += a.x * b.w;
            acc[1][0] += a.y * b.x; acc[1][1] += a.y * b.y; acc[1][2] += a.y * b.z; acc[1][3] += a.y * b.w;
            acc[2][0] += a.z * b.x; acc[2][1] += a.z * b.y; acc[2][2] += a.z * b.z; acc[2][3] += a.z * b.w;
            acc[3][0] += a.w * b.x; acc[3][1] += a.w * b.y; acc[3][2] += a.w * b.z; acc[3][3] += a.w * b.w;
        }
    }

#pragma unroll
    for (int j = 0; j < 4; j++) {
        float bb = bias[col0 + 4 * tx + j];
#pragma unroll
        for (int i = 0; i < 4; i++) {
            C[(size_t)(row0 + 4 * ty + i) * N + col0 + 4 * tx + j] = acc[i][j] + bb;
        }
    }
}

// ---------------------------------------------------------------------------
// RoPE in-place on T viewed as [S, H, 128]; interleaved pairs, gvs = 64.
// ---------------------------------------------------------------------------
__global__ void rope_kernel(float* __restrict__ T, int S, int H)
{
    int idx = blockIdx.x * blockDim.x + threadIdx.x;  // pair index
    int total = S * H * 64;
    if (idx >= total) return;
    int i   = idx & 63;      // pair index within head (0..63)
    int rem = idx >> 6;      // s*H + h
    int s   = rem / H;
    float inv = powf(5000.0f, -(float)i / 64.0f);
    float ang = (float)s * inv;
    float cs = cosf(ang), sn = sinf(ang);
    size_t base = (size_t)rem * 128 + 2 * i;
    float tr = T[base], ti = T[base + 1];
    T[base]     = tr * cs - ti * sn;
    T[base + 1] = tr * sn + ti * cs;
}

// ---------------------------------------------------------------------------
// Attention: one block per (q row, head). Two-pass softmax, scores in LDS.
// Q: [S, 32, 128]; K,V: [S, 8, 128]; O: [S, 32, 128]. Causal j <= qpos.
// ---------------------------------------------------------------------------
__global__ __launch_bounds__(256) void attn_kernel(
    const float* __restrict__ Q, const float* __restrict__ K,
    const float* __restrict__ V, float* __restrict__ O, int S)
{
    __shared__ float qs[128];
    __shared__ float sc[2048];
    __shared__ float red[256];

    const int qpos = blockIdx.x, h = blockIdx.y;
    const int kvh = h >> 2;   // 32 heads / 8 kv heads
    const int tid = threadIdx.x;
    const float scale = 0.08838834764831845f;  // 1/sqrt(128)

    if (tid < 128) qs[tid] = Q[(size_t)qpos * 4096 + h * 128 + tid] * scale;
    __syncthreads();

    const int jend = qpos + 1;

    // pass 1: scores
    float lmax = -1e30f;
    for (int j = tid; j < jend; j += 256) {
        const float* Kp = K + (size_t)j * 1024 + kvh * 128;
        float s = 0.f;
#pragma unroll
        for (int c = 0; c < 32; c++) {
            float4 kv = *(const float4*)(Kp + c * 4);
            s += qs[c * 4 + 0] * kv.x + qs[c * 4 + 1] * kv.y +
                 qs[c * 4 + 2] * kv.z + qs[c * 4 + 3] * kv.w;
        }
        sc[j] = s;
        lmax = fmaxf(lmax, s);
    }
    red[tid] = lmax;
    __syncthreads();
    for (int w = 128; w > 0; w >>= 1) {
        if (tid < w) red[tid] = fmaxf(red[tid], red[tid + w]);
        __syncthreads();
    }
    float gmax = red[0];
    __syncthreads();

    // pass 2: exp + sum
    float lsum = 0.f;
    for (int j = tid; j < jend; j += 256) {
        float p = __expf(sc[j] - gmax);
        sc[j] = p;
        lsum += p;
    }
    red[tid] = lsum;
    __syncthreads();
    for (int w = 128; w > 0; w >>= 1) {
        if (tid < w) red[tid] += red[tid + w];
        __syncthreads();
    }
    float invsum = 1.f / red[0];
    __syncthreads();

    // pass 3: O = P @ V ; tid = half*128 + d
    const int d = tid & 127, half = tid >> 7;
    float o = 0.f;
    for (int j = half; j < jend; j += 2)
        o += sc[j] * V[(size_t)j * 1024 + kvh * 128 + d];
    red[tid] = o;
    __syncthreads();
    if (tid < 128)
        O[(size_t)qpos * 4096 + h * 128 + tid] = (red[tid] + red[tid + 128]) * invsum;
}

// ---------------------------------------------------------------------------
extern "C" void kernel_launch(void* const* d_in, const int* in_sizes, int n_in,
                              void* d_out, int out_size, void* d_ws, size_t ws_size,
                              hipStream_t stream)
{
    const float* x  = (const float*)d_in[0];
    const float* y  = (const float*)d_in[1];
    const float* Wq = (const float*)d_in[2];
    const float* bq = (const float*)d_in[3];
    const float* Wk = (const float*)d_in[4];
    const float* bk = (const float*)d_in[5];
    const float* Wv = (const float*)d_in[6];
    const float* bv = (const float*)d_in[7];
    const float* Wo = (const float*)d_in[8];
    const float* bo = (const float*)d_in[9];
    float* out = (float*)d_out;

    const int S = 2048, D = 4096, GS = 1024;

    // Q lives in d_out (32 MB): fully consumed by attn_kernel before the
    // final GEMM overwrites d_out with the real output (stream-ordered).
    float* Q = out;
    char* ws = (char*)d_ws;
    float* Kt = (float*)(ws);                        // S*GS*4 =  8 MB
    float* Vt = (float*)(ws + 8ull  * 1024 * 1024);  // S*GS*4 =  8 MB
    float* Ao = (float*)(ws + 16ull * 1024 * 1024);  // S*D*4  = 32 MB

    gemm_bias_kernel<<<dim3(D / BN, S / BM), 256, 0, stream>>>(x, Wq, bq, Q, S, D, D);
    gemm_bias_kernel<<<dim3(GS / BN, S / BM), 256, 0, stream>>>(y, Wk, bk, Kt, S, GS, D);
    gemm_bias_kernel<<<dim3(GS / BN, S / BM), 256, 0, stream>>>(y, Wv, bv, Vt, S, GS, D);

    rope_kernel<<<(S * 32 * 64 + 255) / 256, 256, 0, stream>>>(Q, S, 32);
    rope_kernel<<<(S * 8 * 64 + 255) / 256, 256, 0, stream>>>(Kt, S, 8);

    attn_kernel<<<dim3(S, 32), 256, 0, stream>>>(Q, Kt, Vt, Ao, S);

    gemm_bias_kernel<<<dim3(D / BN, S / BM), 256, 0, stream>>>(Ao, Wo, bo, out, S, D, D);
}

// Round 3
// 3690.993 us; speedup vs baseline: 2.9053x; 2.9053x over previous
//
#include <hip/hip_runtime.h>
#include <hip/hip_bf16.h>

// ---------------------------------------------------------------------------
// GEMM: C[M,N] = A[M,K] @ W[K,N] + bias[N]   (fp32 in/accum/out)
// ---------------------------------------------------------------------------
#define BM 64
#define BN 64
#define BK 32
#define LDT 68

__global__ __launch_bounds__(256) void gemm_bias_kernel(
    const float* __restrict__ A, const float* __restrict__ W,
    const float* __restrict__ bias, float* __restrict__ C,
    int M, int N, int K)
{
    __shared__ float As[BK * LDT];
    __shared__ float Bs[BK * LDT];

    const int tid = threadIdx.x;
    const int tx = tid & 15, ty = tid >> 4;
    const int row0 = blockIdx.y * BM;
    const int col0 = blockIdx.x * BN;

    float acc[4][4] = {};

    const int ar = tid >> 2, ac8 = (tid & 3) * 8;
    const int br = tid >> 3, bc8 = (tid & 7) * 8;

    const float* Aptr = A + (size_t)(row0 + ar) * K + ac8;
    const float* Wptr = W + (size_t)br * N + col0 + bc8;

    for (int k0 = 0; k0 < K; k0 += BK) {
        float4 a0 = *(const float4*)(Aptr + k0);
        float4 a1 = *(const float4*)(Aptr + k0 + 4);
        float4 b0 = *(const float4*)(Wptr + (size_t)k0 * N);
        float4 b1 = *(const float4*)(Wptr + (size_t)k0 * N + 4);

        __syncthreads();
        As[(ac8 + 0) * LDT + ar] = a0.x;
        As[(ac8 + 1) * LDT + ar] = a0.y;
        As[(ac8 + 2) * LDT + ar] = a0.z;
        As[(ac8 + 3) * LDT + ar] = a0.w;
        As[(ac8 + 4) * LDT + ar] = a1.x;
        As[(ac8 + 5) * LDT + ar] = a1.y;
        As[(ac8 + 6) * LDT + ar] = a1.z;
        As[(ac8 + 7) * LDT + ar] = a1.w;
        *(float4*)&Bs[br * LDT + bc8]     = b0;
        *(float4*)&Bs[br * LDT + bc8 + 4] = b1;
        __syncthreads();

#pragma unroll
        for (int kk = 0; kk < BK; kk++) {
            float4 a = *(const float4*)&As[kk * LDT + 4 * ty];
            float4 b = *(const float4*)&Bs[kk * LDT + 4 * tx];
            acc[0][0] += a.x * b.x; acc[0][1] += a.x * b.y; acc[0][2] += a.x * b.z; acc[0][3] += a.x * b.w;
            acc[1][0] += a.y * b.x; acc[1][1] += a.y * b.y; acc[1][2] += a.y * b.z; acc[1][3] += a.y * b.w;
            acc[2][0] += a.z * b.x; acc[2][1] += a.z * b.y; acc[2][2] += a.z * b.z; acc[2][3] += a.z * b.w;
            acc[3][0] += a.w * b.x; acc[3][1] += a.w * b.y; acc[3][2] += a.w * b.z; acc[3][3] += a.w * b.w;
        }
    }

#pragma unroll
    for (int j = 0; j < 4; j++) {
        float bb = bias[col0 + 4 * tx + j];
#pragma unroll
        for (int i = 0; i < 4; i++) {
            C[(size_t)(row0 + 4 * ty + i) * N + col0 + 4 * tx + j] = acc[i][j] + bb;
        }
    }
}

// ---------------------------------------------------------------------------
// RoPE in-place on T viewed as [S, H, 128]; interleaved pairs, gvs = 64.
// ---------------------------------------------------------------------------
__global__ void rope_kernel(float* __restrict__ T, int S, int H)
{
    int idx = blockIdx.x * blockDim.x + threadIdx.x;
    int total = S * H * 64;
    if (idx >= total) return;
    int i   = idx & 63;
    int rem = idx >> 6;
    int s   = rem / H;
    float inv = powf(5000.0f, -(float)i / 64.0f);
    float ang = (float)s * inv;
    float cs = cosf(ang), sn = sinf(ang);
    size_t base = (size_t)rem * 128 + 2 * i;
    float tr = T[base], ti = T[base + 1];
    T[base]     = tr * cs - ti * sn;
    T[base + 1] = tr * sn + ti * cs;
}

// ---------------------------------------------------------------------------
// Flash attention. Block = (64-row q-tile, head); 256 threads.
// tx = tid&15: score cols 4tx / O dims 8tx; ty = tid>>4: q rows 4ty (both phases).
// LDS bf16: Qs[d][m] s68, KPs = Ks[d][kv] s68 (union with Ps[kv][m] s68),
// Vs[kv][d] s136.  52,224 B -> 3 blocks/CU (12 waves).
// ---------------------------------------------------------------------------
__device__ __forceinline__ unsigned short f2bf(float f) {
    unsigned int u = __float_as_uint(f);
    u += 0x7fff + ((u >> 16) & 1);       // round-to-nearest-even
    return (unsigned short)(u >> 16);
}
__device__ __forceinline__ unsigned int pack2(float a, float b) {
    return (unsigned int)f2bf(a) | ((unsigned int)f2bf(b) << 16);
}
__device__ __forceinline__ float blo(unsigned int u) { return __uint_as_float(u << 16); }
__device__ __forceinline__ float bhi(unsigned int u) { return __uint_as_float(u & 0xffff0000u); }

__global__ __launch_bounds__(256, 3) void flash_attn_kernel(
    const float* __restrict__ Q, const float* __restrict__ K,
    const float* __restrict__ V, float* __restrict__ O)
{
    __shared__ __align__(16) unsigned short Qs[128 * 68];   // 17408 B
    __shared__ __align__(16) unsigned short KPs[128 * 68];  // 17408 B (Ks / Ps union)
    __shared__ __align__(16) unsigned short Vs[64 * 136];   // 17408 B

    const int tid = threadIdx.x;
    const int tx = tid & 15, ty = tid >> 4;
    const int h = (int)blockIdx.y, kvh = h >> 2;
    const int q0 = (31 - (int)blockIdx.x) * 64;   // long blocks dispatch first
    const float scale = 0.08838834764831845f;     // 1/sqrt(128)

    // stage Q -> Qs[d][m], bf16, pre-scaled. Row pairs pack into dwords.
#pragma unroll
    for (int it = 0; it < 4; ++it) {
        int idx = tid + it * 256;          // 32 rowpairs x 32 d-chunks
        int rp = idx >> 5;
        int dc = (idx & 31) * 4;
        const float* p0 = Q + (size_t)(q0 + 2 * rp) * 4096 + h * 128 + dc;
        float4 a = *(const float4*)p0;
        float4 b = *(const float4*)(p0 + 4096);
        *(unsigned int*)&Qs[(dc + 0) * 68 + 2 * rp] = pack2(a.x * scale, b.x * scale);
        *(unsigned int*)&Qs[(dc + 1) * 68 + 2 * rp] = pack2(a.y * scale, b.y * scale);
        *(unsigned int*)&Qs[(dc + 2) * 68 + 2 * rp] = pack2(a.z * scale, b.z * scale);
        *(unsigned int*)&Qs[(dc + 3) * 68 + 2 * rp] = pack2(a.w * scale, b.w * scale);
    }

    float m_i[4], l_i[4], o[4][8];
#pragma unroll
    for (int i = 0; i < 4; ++i) {
        m_i[i] = -1e30f; l_i[i] = 0.f;
#pragma unroll
        for (int e = 0; e < 8; ++e) o[i][e] = 0.f;
    }

    for (int k0 = 0; k0 <= q0; k0 += 64) {
        __syncthreads();   // prev PV done: KPs/Vs reusable

        // stage K -> KPs[d][kv]
#pragma unroll
        for (int it = 0; it < 4; ++it) {
            int idx = tid + it * 256;
            int rp = idx >> 5;
            int dc = (idx & 31) * 4;
            const float* p0 = K + (size_t)(k0 + 2 * rp) * 1024 + kvh * 128 + dc;
            float4 a = *(const float4*)p0;
            float4 b = *(const float4*)(p0 + 1024);
            *(unsigned int*)&KPs[(dc + 0) * 68 + 2 * rp] = pack2(a.x, b.x);
            *(unsigned int*)&KPs[(dc + 1) * 68 + 2 * rp] = pack2(a.y, b.y);
            *(unsigned int*)&KPs[(dc + 2) * 68 + 2 * rp] = pack2(a.z, b.z);
            *(unsigned int*)&KPs[(dc + 3) * 68 + 2 * rp] = pack2(a.w, b.w);
        }
        // stage V -> Vs[kv][d]
#pragma unroll
        for (int it = 0; it < 8; ++it) {
            int idx = tid + it * 256;
            int row = idx >> 5;
            int dc = (idx & 31) * 4;
            const float* p0 = V + (size_t)(k0 + row) * 1024 + kvh * 128 + dc;
            float4 a = *(const float4*)p0;
            uint2 w;
            w.x = pack2(a.x, a.y);
            w.y = pack2(a.z, a.w);
            *(uint2*)&Vs[row * 136 + dc] = w;
        }
        __syncthreads();

        // S = Q @ K^T (4x4 micro-tile, fp32 accum)
        float s[4][4] = {};
#pragma unroll 8
        for (int dd = 0; dd < 128; ++dd) {
            uint2 qv = *(const uint2*)&Qs[dd * 68 + 4 * ty];
            uint2 kv = *(const uint2*)&KPs[dd * 68 + 4 * tx];
            float a[4] = { blo(qv.x), bhi(qv.x), blo(qv.y), bhi(qv.y) };
            float b[4] = { blo(kv.x), bhi(kv.x), blo(kv.y), bhi(kv.y) };
#pragma unroll
            for (int i = 0; i < 4; ++i)
#pragma unroll
                for (int j = 0; j < 4; ++j) s[i][j] += a[i] * b[j];
        }

        if (k0 == q0) {   // diagonal tile: causal mask
#pragma unroll
            for (int i = 0; i < 4; ++i)
#pragma unroll
                for (int j = 0; j < 4; ++j)
                    if (4 * tx + j > 4 * ty + i) s[i][j] = -1e30f;
        }

        // online softmax update (row groups = 16 tx lanes, shfl butterfly)
        float p[4][4], alpha[4];
#pragma unroll
        for (int i = 0; i < 4; ++i) {
            float rm = fmaxf(fmaxf(s[i][0], s[i][1]), fmaxf(s[i][2], s[i][3]));
            rm = fmaxf(rm, __shfl_xor(rm, 1));
            rm = fmaxf(rm, __shfl_xor(rm, 2));
            rm = fmaxf(rm, __shfl_xor(rm, 4));
            rm = fmaxf(rm, __shfl_xor(rm, 8));
            float mnew = fmaxf(m_i[i], rm);
            alpha[i] = __expf(m_i[i] - mnew);
            float rs = 0.f;
#pragma unroll
            for (int j = 0; j < 4; ++j) { p[i][j] = __expf(s[i][j] - mnew); rs += p[i][j]; }
            rs += __shfl_xor(rs, 1);
            rs += __shfl_xor(rs, 2);
            rs += __shfl_xor(rs, 4);
            rs += __shfl_xor(rs, 8);
            l_i[i] = l_i[i] * alpha[i] + rs;
            m_i[i] = mnew;
        }

        __syncthreads();   // all QK reads of KPs done
#pragma unroll
        for (int i = 0; i < 4; ++i) {
#pragma unroll
            for (int j = 0; j < 4; ++j)
                KPs[(4 * tx + j) * 68 + 4 * ty + i] = f2bf(p[i][j]);   // Ps[kv][m]
#pragma unroll
            for (int e = 0; e < 8; ++e) o[i][e] *= alpha[i];
        }
        __syncthreads();

        // O += P @ V (4x8 micro-tile)
#pragma unroll 4
        for (int kv = 0; kv < 64; ++kv) {
            uint2 pv = *(const uint2*)&KPs[kv * 68 + 4 * ty];
            uint4 vv = *(const uint4*)&Vs[kv * 136 + 8 * tx];
            float pr[4] = { blo(pv.x), bhi(pv.x), blo(pv.y), bhi(pv.y) };
            float vr[8] = { blo(vv.x), bhi(vv.x), blo(vv.y), bhi(vv.y),
                            blo(vv.z), bhi(vv.z), blo(vv.w), bhi(vv.w) };
#pragma unroll
            for (int i = 0; i < 4; ++i)
#pragma unroll
                for (int e = 0; e < 8; ++e) o[i][e] += pr[i] * vr[e];
        }
    }

    // epilogue: O /= l
#pragma unroll
    for (int i = 0; i < 4; ++i) {
        float inv = 1.0f / l_i[i];
        float* op = O + (size_t)(q0 + 4 * ty + i) * 4096 + h * 128 + 8 * tx;
        *(float4*)op       = make_float4(o[i][0] * inv, o[i][1] * inv, o[i][2] * inv, o[i][3] * inv);
        *(float4*)(op + 4) = make_float4(o[i][4] * inv, o[i][5] * inv, o[i][6] * inv, o[i][7] * inv);
    }
}

// ---------------------------------------------------------------------------
extern "C" void kernel_launch(void* const* d_in, const int* in_sizes, int n_in,
                              void* d_out, int out_size, void* d_ws, size_t ws_size,
                              hipStream_t stream)
{
    const float* x  = (const float*)d_in[0];
    const float* y  = (const float*)d_in[1];
    const float* Wq = (const float*)d_in[2];
    const float* bq = (const float*)d_in[3];
    const float* Wk = (const float*)d_in[4];
    const float* bk = (const float*)d_in[5];
    const float* Wv = (const float*)d_in[6];
    const float* bv = (const float*)d_in[7];
    const float* Wo = (const float*)d_in[8];
    const float* bo = (const float*)d_in[9];
    float* out = (float*)d_out;

    const int S = 2048, D = 4096, GS = 1024;

    float* Q = out;                                  // consumed before final GEMM
    char* ws = (char*)d_ws;
    float* Kt = (float*)(ws);                        // 8 MB
    float* Vt = (float*)(ws + 8ull  * 1024 * 1024);  // 8 MB
    float* Ao = (float*)(ws + 16ull * 1024 * 1024);  // 32 MB

    gemm_bias_kernel<<<dim3(D / BN, S / BM), 256, 0, stream>>>(x, Wq, bq, Q, S, D, D);
    gemm_bias_kernel<<<dim3(GS / BN, S / BM), 256, 0, stream>>>(y, Wk, bk, Kt, S, GS, D);
    gemm_bias_kernel<<<dim3(GS / BN, S / BM), 256, 0, stream>>>(y, Wv, bv, Vt, S, GS, D);

    rope_kernel<<<(S * 32 * 64 + 255) / 256, 256, 0, stream>>>(Q, S, 32);
    rope_kernel<<<(S * 8 * 64 + 255) / 256, 256, 0, stream>>>(Kt, S, 8);

    flash_attn_kernel<<<dim3(32, 32), 256, 0, stream>>>(Q, Kt, Vt, Ao);

    gemm_bias_kernel<<<dim3(D / BN, S / BM), 256, 0, stream>>>(Ao, Wo, bo, out, S, D, D);
}

// Round 4
// 1589.267 us; speedup vs baseline: 6.7475x; 2.3225x over previous
//
#include <hip/hip_runtime.h>
#include <hip/hip_bf16.h>

typedef unsigned int uint32;
typedef unsigned short ushort16;
typedef __attribute__((ext_vector_type(8))) __bf16 bf16x8;
typedef __attribute__((ext_vector_type(4))) float f32x4;

__device__ __forceinline__ ushort16 f2bf(float f) {
    uint32 u = __float_as_uint(f);
    u += 0x7fff + ((u >> 16) & 1);       // round-to-nearest-even
    return (ushort16)(u >> 16);
}
// pack two fp32 -> dword of 2 bf16 (a in low half), round-to-nearest (+0x8000)
__device__ __forceinline__ uint32 pack2rn(float a, float b) {
    uint32 ua = __float_as_uint(a) + 0x8000u;
    uint32 ub = __float_as_uint(b) + 0x8000u;
    return __builtin_amdgcn_perm(ub, ua, 0x07060302);  // [a.hi16, b.hi16]
}
__device__ __forceinline__ float blo(uint32 u) { return __uint_as_float(u << 16); }
__device__ __forceinline__ float bhi(uint32 u) { return __uint_as_float(u & 0xffff0000u); }

__device__ __forceinline__ void storeC(float v, float* p) { *p = v; }
__device__ __forceinline__ void storeC(float v, ushort16* p) { *p = f2bf(v); }

// ---------------------------------------------------------------------------
// MFMA GEMM: C[M,N] = A[M,K](fp32) @ W[K,*](fp32) + bias, out OutT (fp32|bf16).
// 128x128 tile, BK=64, 4 waves x (4x4 grid of 16x16x32 bf16 MFMA).
// LDS: As[m][k] / Bs[n][k] bf16, 16B-chunk XOR swizzle (c_phys = c ^ (row&7))
// -> conflict-free ds_read_b128 fragments.  W split: cols < nsplit from W1
// (width ldw), else W2 (supports fused K|V GEMM).
// ---------------------------------------------------------------------------
template <typename OutT>
__global__ __launch_bounds__(256) void gemm_mfma(
    const float* __restrict__ A, const float* __restrict__ W1,
    const float* __restrict__ W2, int ldw,
    const float* __restrict__ b1, const float* __restrict__ b2,
    OutT* __restrict__ C, int N, int K, int nsplit)
{
    __shared__ ushort16 As[128 * 64];
    __shared__ ushort16 Bs[128 * 64];

    const int tid  = threadIdx.x;
    const int lane = tid & 63, wave = tid >> 6;
    const int quad = lane >> 4, m16 = lane & 15;
    const int wm = (wave >> 1) * 64, wn = (wave & 1) * 64;
    const int gm0 = blockIdx.y * 128, gn0 = blockIdx.x * 128;

    const float* Wuse = (gn0 < nsplit) ? W1 : W2;
    const int ncol0 = (gn0 < nsplit) ? gn0 : gn0 - nsplit;

    f32x4 acc[4][4];
#pragma unroll
    for (int i = 0; i < 4; ++i)
#pragma unroll
        for (int j = 0; j < 4; ++j) acc[i][j] = (f32x4){0.f, 0.f, 0.f, 0.f};

    // staging geometry
    const int ra = tid >> 3, cla = tid & 7;            // A: row, logical k-chunk
    const int kpb = tid >> 5, nlb = tid & 31;          // B: k-pair, n-lane
    const float* Ap = A + (size_t)(gm0 + ra) * K + cla * 8;
    const float* Wp = Wuse + (size_t)(2 * kpb) * ldw + ncol0 + nlb;

    for (int k0 = 0; k0 < K; k0 += 64) {
        float4 av0[4], av1[4];
        float bv0[4][4], bv1[4][4];
#pragma unroll
        for (int t = 0; t < 4; ++t) {
            const float* ap = Ap + k0 + (size_t)(32 * t) * K;
            av0[t] = *(const float4*)ap;
            av1[t] = *(const float4*)(ap + 4);
            const float* wp = Wp + (size_t)(k0 + 16 * t) * ldw;
#pragma unroll
            for (int j = 0; j < 4; ++j) {
                bv0[t][j] = wp[32 * j];
                bv1[t][j] = wp[(size_t)ldw + 32 * j];
            }
        }
        __syncthreads();   // previous tile fully consumed
#pragma unroll
        for (int t = 0; t < 4; ++t) {
            int r = ra + 32 * t;
            uint4 st;
            st.x = pack2rn(av0[t].x, av0[t].y);
            st.y = pack2rn(av0[t].z, av0[t].w);
            st.z = pack2rn(av1[t].x, av1[t].y);
            st.w = pack2rn(av1[t].z, av1[t].w);
            *(uint4*)&As[r * 64 + ((cla ^ (r & 7)) * 8)] = st;

            int kp = kpb + 8 * t;
            int clb = kp >> 2, kq = kp & 3;
#pragma unroll
            for (int j = 0; j < 4; ++j) {
                int n = nlb + 32 * j;
                *(uint32*)&Bs[n * 64 + (clb ^ (n & 7)) * 8 + kq * 2] =
                    pack2rn(bv0[t][j], bv1[t][j]);
            }
        }
        __syncthreads();

#pragma unroll
        for (int s = 0; s < 2; ++s) {
            bf16x8 aF[4], bF[4];
            const int cl = s * 4 + quad;
#pragma unroll
            for (int i = 0; i < 4; ++i) {
                int r = wm + i * 16 + m16;
                aF[i] = *(const bf16x8*)&As[r * 64 + (cl ^ (r & 7)) * 8];
                int n = wn + i * 16 + m16;
                bF[i] = *(const bf16x8*)&Bs[n * 64 + (cl ^ (n & 7)) * 8];
            }
#pragma unroll
            for (int i = 0; i < 4; ++i)
#pragma unroll
                for (int j = 0; j < 4; ++j)
                    acc[i][j] = __builtin_amdgcn_mfma_f32_16x16x32_bf16(
                        aF[i], bF[j], acc[i][j], 0, 0, 0);
        }
    }

    // epilogue: D row = quad*4 + reg, col = lane&15
#pragma unroll
    for (int j = 0; j < 4; ++j) {
        int col = gn0 + wn + j * 16 + m16;
        float bb = (col < nsplit) ? b1[col] : b2[col - nsplit];
#pragma unroll
        for (int i = 0; i < 4; ++i) {
            int row0 = gm0 + wm + i * 16 + quad * 4;
#pragma unroll
            for (int r = 0; r < 4; ++r)
                storeC(acc[i][j][r] + bb, C + (size_t)(row0 + r) * N + col);
        }
    }
}

// ---------------------------------------------------------------------------
// RoPE in-place on fp32 Q viewed as [S, 32, 128]; interleaved pairs.
// ---------------------------------------------------------------------------
__global__ void rope_q_kernel(float* __restrict__ T, int S)
{
    int idx = blockIdx.x * blockDim.x + threadIdx.x;
    if (idx >= S * 32 * 64) return;
    int i   = idx & 63;
    int rem = idx >> 6;       // s*32 + h
    int s   = rem >> 5;
    float inv = powf(5000.0f, -(float)i / 64.0f);
    float ang = (float)s * inv;
    float cs = cosf(ang), sn = sinf(ang);
    size_t base = (size_t)rem * 128 + 2 * i;
    float tr = T[base], ti = T[base + 1];
    T[base]     = tr * cs - ti * sn;
    T[base + 1] = tr * sn + ti * cs;
}

// RoPE in-place on bf16 K = cols 0..1023 of KVb [S][2048]
__global__ void rope_k_kernel(ushort16* __restrict__ KVb, int S)
{
    int idx = blockIdx.x * blockDim.x + threadIdx.x;
    if (idx >= S * 8 * 64) return;
    int i   = idx & 63;
    int rem = idx >> 6;       // s*8 + h
    int s   = rem >> 3, h = rem & 7;
    float inv = powf(5000.0f, -(float)i / 64.0f);
    float ang = (float)s * inv;
    float cs = cosf(ang), sn = sinf(ang);
    uint32* p = (uint32*)&KVb[(size_t)s * 2048 + h * 128 + 2 * i];
    uint32 u = *p;
    float tr = blo(u), ti = bhi(u);
    *p = pack2rn(tr * cs - ti * sn, tr * sn + ti * cs);
}

// ---------------------------------------------------------------------------
// Flash attention. Block = (64-row q-tile, head); 256 threads.
// Q fp32 [S][4096]; KVb bf16 [S][2048] = K|V fused; O fp32 [S][4096].
// ---------------------------------------------------------------------------
__global__ __launch_bounds__(256, 3) void flash_attn_kernel(
    const float* __restrict__ Q, const ushort16* __restrict__ KVb,
    float* __restrict__ O)
{
    __shared__ __align__(16) ushort16 Qs[128 * 68];   // [d][m-pairs]
    __shared__ __align__(16) ushort16 KPs[128 * 68];  // Ks[d][kv] / Ps[kv][m] union
    __shared__ __align__(16) ushort16 Vs[64 * 136];   // [kv][d]

    const int tid = threadIdx.x;
    const int tx = tid & 15, ty = tid >> 4;
    const int h = (int)blockIdx.y, kvh = h >> 2;
    const int q0 = (31 - (int)blockIdx.x) * 64;   // long blocks dispatch first
    const float scale = 0.08838834764831845f;     // 1/sqrt(128)

    const ushort16* Kbase = KVb + kvh * 128;
    const ushort16* Vbase = KVb + 1024 + kvh * 128;

    // stage Q (fp32) -> Qs[d][m], bf16, pre-scaled
#pragma unroll
    for (int it = 0; it < 4; ++it) {
        int idx = tid + it * 256;
        int rp = idx >> 5;
        int dc = (idx & 31) * 4;
        const float* p0 = Q + (size_t)(q0 + 2 * rp) * 4096 + h * 128 + dc;
        float4 a = *(const float4*)p0;
        float4 b = *(const float4*)(p0 + 4096);
        *(uint32*)&Qs[(dc + 0) * 68 + 2 * rp] = pack2rn(a.x * scale, b.x * scale);
        *(uint32*)&Qs[(dc + 1) * 68 + 2 * rp] = pack2rn(a.y * scale, b.y * scale);
        *(uint32*)&Qs[(dc + 2) * 68 + 2 * rp] = pack2rn(a.z * scale, b.z * scale);
        *(uint32*)&Qs[(dc + 3) * 68 + 2 * rp] = pack2rn(a.w * scale, b.w * scale);
    }

    float m_i[4], l_i[4], o[4][8];
#pragma unroll
    for (int i = 0; i < 4; ++i) {
        m_i[i] = -1e30f; l_i[i] = 0.f;
#pragma unroll
        for (int e = 0; e < 8; ++e) o[i][e] = 0.f;
    }

    for (int k0 = 0; k0 <= q0; k0 += 64) {
        __syncthreads();   // prev PV done: KPs/Vs reusable

        // stage K (bf16) -> KPs[d][kv]: interleave row pairs via v_perm
#pragma unroll
        for (int it = 0; it < 2; ++it) {
            int idx = tid + it * 256;          // 0..511
            int rp = idx >> 4;                 // 0..31
            int dc = (idx & 15) * 8;           // 0..120
            const ushort16* p0 = Kbase + (size_t)(k0 + 2 * rp) * 2048 + dc;
            uint4 a = *(const uint4*)p0;
            uint4 b = *(const uint4*)(p0 + 2048);
            uint32 aw[4] = {a.x, a.y, a.z, a.w}, bw[4] = {b.x, b.y, b.z, b.w};
#pragma unroll
            for (int t = 0; t < 4; ++t) {
                *(uint32*)&KPs[(dc + 2 * t)     * 68 + 2 * rp] =
                    __builtin_amdgcn_perm(bw[t], aw[t], 0x05040100);
                *(uint32*)&KPs[(dc + 2 * t + 1) * 68 + 2 * rp] =
                    __builtin_amdgcn_perm(bw[t], aw[t], 0x07060302);
            }
        }
        // stage V (bf16) -> Vs[kv][d]: straight 16B copies
#pragma unroll
        for (int it = 0; it < 4; ++it) {
            int idx = tid + it * 256;
            int row = idx >> 4;                // 0..63
            int dc = (idx & 15) * 8;
            *(uint4*)&Vs[row * 136 + dc] =
                *(const uint4*)(Vbase + (size_t)(k0 + row) * 2048 + dc);
        }
        __syncthreads();

        // S = Q @ K^T (4x4 micro-tile, fp32 accum)
        float s[4][4] = {};
#pragma unroll 8
        for (int dd = 0; dd < 128; ++dd) {
            uint2 qv = *(const uint2*)&Qs[dd * 68 + 4 * ty];
            uint2 kv = *(const uint2*)&KPs[dd * 68 + 4 * tx];
            float a[4] = { blo(qv.x), bhi(qv.x), blo(qv.y), bhi(qv.y) };
            float b[4] = { blo(kv.x), bhi(kv.x), blo(kv.y), bhi(kv.y) };
#pragma unroll
            for (int i = 0; i < 4; ++i)
#pragma unroll
                for (int j = 0; j < 4; ++j) s[i][j] += a[i] * b[j];
        }

        if (k0 == q0) {   // diagonal tile: causal mask
#pragma unroll
            for (int i = 0; i < 4; ++i)
#pragma unroll
                for (int j = 0; j < 4; ++j)
                    if (4 * tx + j > 4 * ty + i) s[i][j] = -1e30f;
        }

        // online softmax (row groups = 16 tx lanes, shfl butterfly)
        float p[4][4], alpha[4];
#pragma unroll
        for (int i = 0; i < 4; ++i) {
            float rm = fmaxf(fmaxf(s[i][0], s[i][1]), fmaxf(s[i][2], s[i][3]));
            rm = fmaxf(rm, __shfl_xor(rm, 1));
            rm = fmaxf(rm, __shfl_xor(rm, 2));
            rm = fmaxf(rm, __shfl_xor(rm, 4));
            rm = fmaxf(rm, __shfl_xor(rm, 8));
            float mnew = fmaxf(m_i[i], rm);
            alpha[i] = __expf(m_i[i] - mnew);
            float rs = 0.f;
#pragma unroll
            for (int j = 0; j < 4; ++j) { p[i][j] = __expf(s[i][j] - mnew); rs += p[i][j]; }
            rs += __shfl_xor(rs, 1);
            rs += __shfl_xor(rs, 2);
            rs += __shfl_xor(rs, 4);
            rs += __shfl_xor(rs, 8);
            l_i[i] = l_i[i] * alpha[i] + rs;
            m_i[i] = mnew;
        }

        __syncthreads();   // all QK reads of KPs done
#pragma unroll
        for (int i = 0; i < 4; ++i) {
#pragma unroll
            for (int j = 0; j < 4; ++j)
                KPs[(4 * tx + j) * 68 + 4 * ty + i] = f2bf(p[i][j]);   // Ps[kv][m]
#pragma unroll
            for (int e = 0; e < 8; ++e) o[i][e] *= alpha[i];
        }
        __syncthreads();

        // O += P @ V (4x8 micro-tile)
#pragma unroll 4
        for (int kv = 0; kv < 64; ++kv) {
            uint2 pv = *(const uint2*)&KPs[kv * 68 + 4 * ty];
            uint4 vv = *(const uint4*)&Vs[kv * 136 + 8 * tx];
            float pr[4] = { blo(pv.x), bhi(pv.x), blo(pv.y), bhi(pv.y) };
            float vr[8] = { blo(vv.x), bhi(vv.x), blo(vv.y), bhi(vv.y),
                            blo(vv.z), bhi(vv.z), blo(vv.w), bhi(vv.w) };
#pragma unroll
            for (int i = 0; i < 4; ++i)
#pragma unroll
                for (int e = 0; e < 8; ++e) o[i][e] += pr[i] * vr[e];
        }
    }

    // epilogue: O /= l
#pragma unroll
    for (int i = 0; i < 4; ++i) {
        float inv = 1.0f / l_i[i];
        float* op = O + (size_t)(q0 + 4 * ty + i) * 4096 + h * 128 + 8 * tx;
        *(float4*)op       = make_float4(o[i][0] * inv, o[i][1] * inv, o[i][2] * inv, o[i][3] * inv);
        *(float4*)(op + 4) = make_float4(o[i][4] * inv, o[i][5] * inv, o[i][6] * inv, o[i][7] * inv);
    }
}

// ---------------------------------------------------------------------------
extern "C" void kernel_launch(void* const* d_in, const int* in_sizes, int n_in,
                              void* d_out, int out_size, void* d_ws, size_t ws_size,
                              hipStream_t stream)
{
    const float* x  = (const float*)d_in[0];
    const float* y  = (const float*)d_in[1];
    const float* Wq = (const float*)d_in[2];
    const float* bq = (const float*)d_in[3];
    const float* Wk = (const float*)d_in[4];
    const float* bk = (const float*)d_in[5];
    const float* Wv = (const float*)d_in[6];
    const float* bv = (const float*)d_in[7];
    const float* Wo = (const float*)d_in[8];
    const float* bo = (const float*)d_in[9];
    float* out = (float*)d_out;

    const int S = 2048, D = 4096;

    // Q fp32 lives in d_out (consumed by attn before final GEMM overwrites).
    float* Q = out;
    char* ws = (char*)d_ws;
    float*    Ao  = (float*)ws;                            // 32 MB fp32
    ushort16* KVb = (ushort16*)(ws + 34ull * 1024 * 1024); // 8 MB bf16 [S][2048]

    // Q = x @ Wq + bq   (fp32 out, 512 blocks)
    gemm_mfma<float><<<dim3(32, 16), 256, 0, stream>>>(
        x, Wq, Wq, D, bq, bq, Q, D, D, D);
    // KV = y @ [Wk|Wv] + [bk|bv]  (bf16 out, fused N=2048)
    gemm_mfma<ushort16><<<dim3(16, 16), 256, 0, stream>>>(
        y, Wk, Wv, 1024, bk, bv, KVb, 2048, D, 1024);

    rope_q_kernel<<<(S * 32 * 64 + 255) / 256, 256, 0, stream>>>(Q, S);
    rope_k_kernel<<<(S * 8 * 64 + 255) / 256, 256, 0, stream>>>(KVb, S);

    flash_attn_kernel<<<dim3(32, 32), 256, 0, stream>>>(Q, KVb, Ao);

    // out = Ao @ Wo + bo
    gemm_mfma<float><<<dim3(32, 16), 256, 0, stream>>>(
        Ao, Wo, Wo, D, bo, bo, out, D, D, D);
}